// Round 9
// baseline (174.057 us; speedup 1.0000x reference)
//
#include <hip/hip_runtime.h>
#include <hip/hip_bf16.h>
#include <math.h>

#define GN 8192
#define GD 128
#define GH 2
#define GK 3
#define NEG_SLOPE 0.2f
#define LN_EPS 1e-5f

using short8  = __attribute__((ext_vector_type(8)))  short;
using float16 = __attribute__((ext_vector_type(16))) float;
using f32x4   = __attribute__((ext_vector_type(4)))  float;

__device__ __forceinline__ float wred(float v) {
    #pragma unroll
    for (int o = 32; o > 0; o >>= 1) v += __shfl_xor(v, o, 64);
    return v;
}

// monotone float->uint encoding (ascending float -> ascending uint)
__device__ __forceinline__ unsigned fenc(float f) {
    unsigned b = __float_as_uint(f);
    return (b & 0x80000000u) ? ~b : (b | 0x80000000u);
}

__device__ __forceinline__ float rawbf2f(unsigned short s) {
    return __uint_as_float(((unsigned)s) << 16);
}
__device__ __forceinline__ unsigned short f2rawbf(float f) {
    __hip_bfloat16 b = __float2bfloat16(f);
    unsigned short r; __builtin_memcpy(&r, &b, 2);
    return r;
}
__device__ __forceinline__ unsigned umin2(unsigned a, unsigned b) { return a < b ? a : b; }
__device__ __forceinline__ unsigned umax2(unsigned a, unsigned b) { return a > b ? a : b; }

// FUSED pre-pass + conv (roles block-disjoint):
//   b <  128     : transpose W into MFMA-B bf16 hi/lo
//   b in [128,132): u vectors uvec[b][d] = sum_c W[d][h*128+c] * v[h][c]
//   b >= 132     : per-row conv: sq, xa=[-2x | hi(sq+512) lo], xb=[x | 1 1],
//                  cnt/curs zero-init (CSR path restored).
__global__ void k_prep(const float* __restrict__ W, const float* __restrict__ att_src,
                       const float* __restrict__ att_dst, const float* __restrict__ x,
                       unsigned short* __restrict__ Wth, unsigned short* __restrict__ Wtl,
                       float* __restrict__ uvec, float* __restrict__ sq,
                       unsigned short* __restrict__ xa, unsigned short* __restrict__ xb,
                       int* __restrict__ cnt, int* __restrict__ curs) {
    __shared__ float vs[128];
    int b = blockIdx.x, t = threadIdx.x;
    if (b < 128) {
        int e = b * 256 + t;   // 32768
        int d = e >> 8, j = e & 255;
        int h = j >> 7, c = j & 127;
        int k = h * 128 + d;
        float w = W[e];
        unsigned short hi = f2rawbf(w);
        Wth[c * 256 + k] = hi;
        Wtl[c * 256 + k] = f2rawbf(w - rawbf2f(hi));
    } else if (b < 132) {
        int bb = b - 128;
        int h = bb & 1;
        const float* v = (bb < 2 ? att_src : att_dst) + h * 128;
        if (t < 128) vs[t] = v[t];
        __syncthreads();
        int d = t >> 1, half = t & 1;
        const float* wr = W + (size_t)d * 256 + h * 128 + half * 64;
        float s = 0.f;
        for (int c = 0; c < 64; c++) s += wr[c] * vs[half * 64 + c];
        s += __shfl_xor(s, 1, 64);
        if (half == 0) uvec[bb * 128 + d] = s;
    } else {
        int row = (b - 132) * 4 + (t >> 6);
        int lane = t & 63;
        const float* xr = x + (size_t)row * GD;
        float a0 = xr[lane], a1 = xr[lane + 64];
        float s = wred(a0 * a0 + a1 * a1);
        unsigned short* ar = xa + (size_t)row * 144;
        unsigned short* br = xb + (size_t)row * 144;
        ar[lane] = f2rawbf(-2.f * a0); ar[lane + 64] = f2rawbf(-2.f * a1);
        br[lane] = f2rawbf(a0);        br[lane + 64] = f2rawbf(a1);
        if (lane < 16) {
            unsigned short av = 0, bv = 0;
            if (lane == 0)      { av = f2rawbf(s + 512.f); bv = 0x3F80; }
            else if (lane == 1) { float hi = rawbf2f(f2rawbf(s + 512.f));
                                  av = f2rawbf(s + 512.f - hi); bv = 0x3F80; }
            ar[128 + lane] = av; br[128 + lane] = bv;
            if (lane == 0) {
                sq[row] = s;
                cnt[row] = 0; curs[row] = 0;
            }
        }
    }
}

// top-4 insert network step (order-independent, keys distinct)
#define INS(U0,U1,U2,U3,kk) do {                                   \
    unsigned m0_ = umax2(U0,(kk)); U0 = umin2(U0,(kk));            \
    unsigned m1_ = umax2(U1,m0_);  U1 = umin2(U1,m0_);             \
    unsigned m2_ = umax2(U2,m1_);  U2 = umin2(U2,m1_);             \
    U3 = umin2(U3,m2_); } while(0)

// quad-granular guarded insert of one float16 accumulator.
// A quad whose masked min > U3 cannot change U0..U3 -> skipping is bit-exact.
#define TOPK16(A, U0,U1,U2,U3, rbase) do {                                        \
    _Pragma("unroll")                                                             \
    for (int q4_ = 0; q4_ < 4; q4_++) {                                           \
        unsigned c0_ = __float_as_uint((A)[q4_ * 4 + 0]);                         \
        unsigned c1_ = __float_as_uint((A)[q4_ * 4 + 1]);                         \
        unsigned c2_ = __float_as_uint((A)[q4_ * 4 + 2]);                         \
        unsigned c3_ = __float_as_uint((A)[q4_ * 4 + 3]);                         \
        unsigned qm_ = umin2(umin2(c0_, c1_), umin2(c2_, c3_));                   \
        if ((qm_ & 0xFFFFE000u) <= U3) {                                          \
            INS(U0,U1,U2,U3, (c0_ & 0xFFFFE000u) | (unsigned)((rbase) + 0 + 8 * q4_)); \
            INS(U0,U1,U2,U3, (c1_ & 0xFFFFE000u) | (unsigned)((rbase) + 1 + 8 * q4_)); \
            INS(U0,U1,U2,U3, (c2_ & 0xFFFFE000u) | (unsigned)((rbase) + 2 + 8 * q4_)); \
            INS(U0,U1,U2,U3, (c3_ & 0xFFFFE000u) | (unsigned)((rbase) + 3 + 8 * q4_)); \
        }                                                                         \
    } } while(0)

// MFMA candidate kNN. score'_ij = 512 + sq_i - 2 x_i.x_j (> 0 -> raw bits monotone).
// grid (64,33): by<32: 128 cols x one 256-row superblock per block (top-4/sb/col
// -> 128 keys per col); by==32: a_s/a_d attention-dot tail (backfills the gemm
// drain; identical math to the former refine tail; consumed by k_fill only).
// 32-row half-tiles double-buffered in 2x9 KB LDS; launch_bounds(256,6).
#define STAGE_HALF(buf, rowbase)                                                  \
    do {                                                                          \
        _Pragma("unroll")                                                         \
        for (int s_ = 0; s_ < 3; s_++) {                                          \
            if (s_ < 2 || t < 64) {                                               \
                int q_ = s_ * 256 + t;     /* 0..575: 18 chunks x 32 rows */      \
                int kb_ = q_ >> 5, r_ = q_ & 31;                                  \
                __builtin_amdgcn_global_load_lds(                                 \
                    (const __attribute__((address_space(1))) unsigned*)           \
                        (xa + (size_t)((rowbase) + r_) * 144 + kb_ * 8),          \
                    (__attribute__((address_space(3))) unsigned*)&At[(buf)][q_ * 8],\
                    16, 0, 0);                                                    \
            }                                                                     \
        }                                                                         \
    } while (0)

__launch_bounds__(256, 6)
__global__ void k_gemm_topk(const unsigned short* __restrict__ xa,
                            const unsigned short* __restrict__ xb,
                            const float* __restrict__ x, const float* __restrict__ uvec,
                            unsigned* __restrict__ cand,
                            float* __restrict__ a_s, float* __restrict__ a_d) {
    __shared__ __align__(16) unsigned short At[2][18 * 32 * 8];  // 2 x 9 KB
    int t = threadIdx.x;

    if (blockIdx.y == 32) {
        // a_s/a_d tail: 64 blocks x 128 rows; per wave 32 rows, u-vectors hoisted
        int wv = t >> 6, lane = t & 63;
        float u0 = uvec[lane],       u1 = uvec[64 + lane];
        float u2 = uvec[128 + lane], u3 = uvec[192 + lane];
        float u4 = uvec[256 + lane], u5 = uvec[320 + lane];
        float u6 = uvec[384 + lane], u7 = uvec[448 + lane];
        int row0 = blockIdx.x * 128 + wv * 32;
        for (int rr = 0; rr < 32; rr++) {
            int row = row0 + rr;
            const float* xr = x + (size_t)row * GD;
            float a0 = xr[lane], a1 = xr[lane + 64];
            float s0 = wred(a0 * u0 + a1 * u1);
            float s1 = wred(a0 * u2 + a1 * u3);
            float d0 = wred(a0 * u4 + a1 * u5);
            float d1 = wred(a0 * u6 + a1 * u7);
            if (lane == 0) {
                a_s[row * 2] = s0; a_s[row * 2 + 1] = s1;
                a_d[row * 2] = d0; a_d[row * 2 + 1] = d1;
            }
        }
        return;
    }

    int w = t >> 6, lane = t & 63, h = lane >> 5, n = lane & 31;
    int col = blockIdx.x * 128 + w * 32 + n;
    int sb = blockIdx.y;                 // 0..31, 256-row superblock
    int rb0 = sb * 256;

    short8 bfrag[9];
    #pragma unroll
    for (int kc = 0; kc < 9; kc++)
        bfrag[kc] = *(const short8*)(xb + (size_t)col * 144 + (2 * kc + h) * 8);

    STAGE_HALF(0, rb0);
    asm volatile("s_waitcnt vmcnt(0)" ::: "memory");
    __builtin_amdgcn_s_barrier();

    unsigned T0 = 0xFFFFFFFFu, T1 = 0xFFFFFFFFu, T2 = 0xFFFFFFFFu, T3 = 0xFFFFFFFFu;

    #pragma unroll 1
    for (int ht = 0; ht < 8; ht++) {
        int cur = ht & 1;
        if (ht < 7) STAGE_HALF(cur ^ 1, rb0 + (ht + 1) * 32);

        float16 acc = (float16)(0.f);

        #pragma unroll
        for (int kc = 0; kc < 9; kc++) {
            short8 a = *(const short8*)&At[cur][(((2 * kc + h) * 32) + n) * 8];
            acc = __builtin_amdgcn_mfma_f32_32x32x16_bf16(a, bfrag[kc], acc, 0, 0, 0);
        }

        int rbq = rb0 + ht * 32 + 4 * h;
        TOPK16(acc, T0, T1, T2, T3, rbq);

        if (ht < 7) {
            asm volatile("s_waitcnt vmcnt(0)" ::: "memory");
            __builtin_amdgcn_s_barrier();
        }
    }

    // merge the two 32-row halves (h=0/1) of each column, write top-4
    unsigned p0 = (unsigned)__shfl_xor((int)T0, 32), p1 = (unsigned)__shfl_xor((int)T1, 32),
             p2 = (unsigned)__shfl_xor((int)T2, 32), p3 = (unsigned)__shfl_xor((int)T3, 32);
    INS(T0,T1,T2,T3, p0); INS(T0,T1,T2,T3, p1);
    INS(T0,T1,T2,T3, p2); INS(T0,T1,T2,T3, p3);
    if (h == 0) {
        uint4 o = make_uint4(T0, T1, T2, T3);
        *(uint4*)(cand + (size_t)col * 128 + sb * 4) = o;
    }
}

__device__ __forceinline__ int clampN(int v) {
    return v < 0 ? 0 : (v >= GN ? GN - 1 : v);
}

// two-stage refine. One wave per node.
// stage 1: top-16 of the 128 keys (2 per lane; keys globally distinct:
//          disjoint row bits) — 16 select-and-remove min-butterflies.
// stage 2: exact fp32 d2 for the 16 survivors; 4-lane group per candidate;
//          top-3 lexicographic (d2, idx); cnt atomics for the CSR build.
__global__ void k_refine(const unsigned* __restrict__ cand,
                         const float* __restrict__ x, const float* __restrict__ sq,
                         int* __restrict__ fidx, int* __restrict__ cnt) {
    int t = threadIdx.x, wv = t >> 6, lane = t & 63;
    int j = blockIdx.x * 4 + wv;
    int c = lane >> 2, g = lane & 3;

    unsigned k0 = cand[(size_t)j * 128 + lane];
    unsigned k1 = cand[(size_t)j * 128 + 64 + lane];
    int myidx = 0;
    #pragma unroll
    for (int r = 0; r < 16; r++) {
        unsigned m = umin2(k0, k1);
        #pragma unroll
        for (int o = 32; o > 0; o >>= 1)
            m = umin2(m, (unsigned)__shfl_xor((int)m, o, 64));
        myidx = (c == r) ? (int)(m & 8191u) : myidx;
        k0 = (k0 == m) ? 0xFFFFFFFFu : k0;
        k1 = (k1 == m) ? 0xFFFFFFFFu : k1;
    }

    const float* xi = x + (size_t)myidx * GD + g * 32;
    const float* xj = x + (size_t)j * GD + g * 32;
    float p = 0.f;
    #pragma unroll
    for (int d4 = 0; d4 < 8; d4++) {
        float4 a = *(const float4*)(xi + d4 * 4);
        float4 b = *(const float4*)(xj + d4 * 4);
        p += a.x * b.x + a.y * b.y + a.z * b.z + a.w * b.w;
    }
    p += __shfl_xor(p, 1, 64);
    p += __shfl_xor(p, 2, 64);
    float d2 = sq[j] + sq[myidx] - 2.f * p;
    unsigned long long key = ((unsigned long long)fenc(d2) << 32) | (unsigned)myidx;

    int out3[3];
    #pragma unroll
    for (int r = 0; r < 3; r++) {
        unsigned long long k = key;
        #pragma unroll
        for (int o = 4; o <= 32; o <<= 1) {
            unsigned long long other = __shfl_xor(k, o, 64);
            k = k < other ? k : other;
        }
        out3[r] = (int)(unsigned)(k & 8191u);
        key = (key == k) ? ~0ull : key;   // group keys removed together (idx unique)
    }
    if (lane == 0) {
        int i0 = clampN(out3[0]), i1 = clampN(out3[1]), i2 = clampN(out3[2]);
        fidx[j * 3 + 0] = i0; fidx[j * 3 + 1] = i1; fidx[j * 3 + 2] = i2;
        atomicAdd(&cnt[i0], 1); atomicAdd(&cnt[i1], 1); atomicAdd(&cnt[i2], 1);
    }
}

// FUSED scan + fill: every block redundantly computes the full 8192 prefix
// scan of cnt (deterministic integer scan -> identical in all blocks; 32 KB
// L2-hot), keeps it in LDS, and block 0 additionally writes global offs for
// k_out. Then the per-edge CSR scatter proceeds against the LDS offsets.
__global__ void k_fill(const int* __restrict__ cnt, int* __restrict__ offs,
                       const int* __restrict__ fidx,
                       int* __restrict__ cursor, int* __restrict__ elist,
                       const float* __restrict__ a_s, const float* __restrict__ a_d,
                       float2* __restrict__ ew) {
    __shared__ __align__(16) int buf[8192];
    __shared__ int wtot[4];
    int t = threadIdx.x, wv = t >> 6, lane = t & 63;

    #pragma unroll
    for (int j = 0; j < 8; j++)
        ((int4*)buf)[j * 256 + t] = ((const int4*)cnt)[j * 256 + t];
    __syncthreads();
    int loc[32], s = 0;
    #pragma unroll
    for (int k = 0; k < 32; k++) { loc[k] = s; s += buf[t * 32 + k]; }
    int inc = s;
    #pragma unroll
    for (int d = 1; d < 64; d <<= 1) {
        int nv = __shfl_up(inc, d, 64);
        if (lane >= d) inc += nv;
    }
    if (lane == 63) wtot[wv] = inc;
    __syncthreads();
    int wbase = 0;
    #pragma unroll
    for (int wq = 0; wq < 4; wq++) wbase += (wq < wv) ? wtot[wq] : 0;
    int base = wbase + inc - s;
    #pragma unroll
    for (int k = 0; k < 32; k++) buf[t * 32 + k] = base + loc[k];
    __syncthreads();
    if (blockIdx.x == 0) {
        #pragma unroll
        for (int j = 0; j < 8; j++)
            ((int4*)offs)[j * 256 + t] = ((int4*)buf)[j * 256 + t];
        if (t == 255) offs[GN] = wtot[0] + wtot[1] + wtot[2] + wtot[3];
    }

    int eid = blockIdx.x * 256 + t;
    int i = clampN(fidx[eid]);
    int src = eid / 3;
    float2 as = ((const float2*)a_s)[src];
    float2 ad = ((const float2*)a_d)[i];
    float e0 = as.x + ad.x; e0 = e0 >= 0.f ? e0 : NEG_SLOPE * e0;
    float e1 = as.y + ad.y; e1 = e1 >= 0.f ? e1 : NEG_SLOPE * e1;
    float w0 = expf(e0), w1 = expf(e1);
    int pos = atomicAdd(&cursor[i], 1);
    int slot = buf[i] + pos;
    if (slot < GN * GK) { elist[slot] = src; ew[slot] = make_float2(w0, w1); }
}

// fused aggregation: 16 nodes/block, 512 threads (8 waves; 2 nodes/wave).
__launch_bounds__(512, 4)
__global__ void k_out(const int* __restrict__ offs, const int* __restrict__ elst,
                      const float2* __restrict__ ew,
                      const float* __restrict__ x,
                      const unsigned short* __restrict__ Wth,
                      const unsigned short* __restrict__ Wtl,
                      const float* __restrict__ bias, const float* __restrict__ gamma,
                      const float* __restrict__ beta, float* __restrict__ out) {
    __shared__ unsigned short zh[16][264];
    __shared__ unsigned short zl[16][264];
    __shared__ float os[16][132];
    int t = threadIdx.x, i0 = blockIdx.x * 16;
    int wv = t >> 6, lane = t & 63;
    int eslot = lane >> 3, g = lane & 7;

    #pragma unroll
    for (int pp = 0; pp < 2; pp++) {
        int r = wv * 2 + pp, node = i0 + r;
        int s = offs[node], e = offs[node + 1];
        float acc0[16], acc1[16];
        #pragma unroll
        for (int q = 0; q < 16; q++) { acc0[q] = 0.f; acc1[q] = 0.f; }
        float w0s = 0.f, w1s = 0.f;
        for (int k0 = s; k0 < e; k0 += 8) {
            int k = k0 + eslot;
            bool valid = k < e;
            int j = valid ? elst[k] : 0;
            float2 wv2 = valid ? ew[k] : make_float2(0.f, 0.f);
            const float* xr = x + (size_t)j * GD + g * 16;
            float4 x0 = *(const float4*)(xr);
            float4 x1 = *(const float4*)(xr + 4);
            float4 x2 = *(const float4*)(xr + 8);
            float4 x3 = *(const float4*)(xr + 12);
            float xv[16] = {x0.x, x0.y, x0.z, x0.w, x1.x, x1.y, x1.z, x1.w,
                            x2.x, x2.y, x2.z, x2.w, x3.x, x3.y, x3.z, x3.w};
            #pragma unroll
            for (int q = 0; q < 16; q++) {
                acc0[q] += wv2.x * xv[q];
                acc1[q] += wv2.y * xv[q];
            }
            w0s += wv2.x; w1s += wv2.y;
        }
        #pragma unroll
        for (int m = 8; m <= 32; m <<= 1) {
            #pragma unroll
            for (int q = 0; q < 16; q++) {
                acc0[q] += __shfl_xor(acc0[q], m, 64);
                acc1[q] += __shfl_xor(acc1[q], m, 64);
            }
            w0s += __shfl_xor(w0s, m, 64);
            w1s += __shfl_xor(w1s, m, 64);
        }
        if (lane < 8) {
            float dn0 = 0.5f / w0s, dn1 = 0.5f / w1s;
            #pragma unroll
            for (int q = 0; q < 16; q += 2) {
                float a0 = acc0[q] * dn0, a1 = acc0[q + 1] * dn0;
                unsigned short h0 = f2rawbf(a0), h1 = f2rawbf(a1);
                *(unsigned*)&zh[r][lane * 16 + q] = (unsigned)h0 | ((unsigned)h1 << 16);
                *(unsigned*)&zl[r][lane * 16 + q] =
                    (unsigned)f2rawbf(a0 - rawbf2f(h0)) |
                    ((unsigned)f2rawbf(a1 - rawbf2f(h1)) << 16);
                float b0 = acc1[q] * dn1, b1 = acc1[q + 1] * dn1;
                unsigned short p0 = f2rawbf(b0), p1 = f2rawbf(b1);
                *(unsigned*)&zh[r][128 + lane * 16 + q] = (unsigned)p0 | ((unsigned)p1 << 16);
                *(unsigned*)&zl[r][128 + lane * 16 + q] =
                    (unsigned)f2rawbf(b0 - rawbf2f(p0)) |
                    ((unsigned)f2rawbf(b1 - rawbf2f(p1)) << 16);
            }
        }
    }
    __syncthreads();

    {
        int qd = lane >> 4, an = lane & 15;
        int c = wv * 16 + an;
        f32x4 acc = {0.f, 0.f, 0.f, 0.f};
        #pragma unroll
        for (int s = 0; s < 8; s++) {
            int ko = s * 32 + qd * 8;
            short8 ah = *(const short8*)&zh[an][ko];
            short8 al = *(const short8*)&zl[an][ko];
            short8 bh = *(const short8*)(Wth + (size_t)c * 256 + ko);
            short8 bl = *(const short8*)(Wtl + (size_t)c * 256 + ko);
            acc = __builtin_amdgcn_mfma_f32_16x16x32_bf16(ah, bh, acc, 0, 0, 0);
            acc = __builtin_amdgcn_mfma_f32_16x16x32_bf16(al, bh, acc, 0, 0, 0);
            acc = __builtin_amdgcn_mfma_f32_16x16x32_bf16(ah, bl, acc, 0, 0, 0);
        }
        #pragma unroll
        for (int r = 0; r < 4; r++) os[qd * 4 + r][c] = acc[r];
    }
    __syncthreads();

    #pragma unroll
    for (int pp = 0; pp < 2; pp++) {
        int r = wv * 2 + pp, node = i0 + r;
        float y0 = os[r][lane] + bias[lane];
        float y1 = os[r][lane + 64] + bias[lane + 64];
        float mu = wred(y0 + y1) * (1.f / 128.f);
        float c0 = y0 - mu, c1 = y1 - mu;
        float var = wred(c0 * c0 + c1 * c1) * (1.f / 128.f);
        float rs2 = 1.f / sqrtf(var + LN_EPS);
        float n0 = c0 * rs2 * gamma[lane] + beta[lane];
        float n1 = c1 * rs2 * gamma[lane + 64] + beta[lane + 64];
        n0 = n0 > 0.f ? n0 : 0.f;
        n1 = n1 > 0.f ? n1 : 0.f;
        out[(size_t)node * GD + lane]      = x[(size_t)node * GD + lane] + n0;
        out[(size_t)node * GD + lane + 64] = x[(size_t)node * GD + lane + 64] + n1;
    }
}

extern "C" void kernel_launch(void* const* d_in, const int* in_sizes, int n_in,
                              void* d_out, int out_size, void* d_ws, size_t ws_size,
                              hipStream_t stream) {
    const float* x       = (const float*)d_in[0];
    const float* W       = (const float*)d_in[2];
    const float* att_src = (const float*)d_in[3];
    const float* att_dst = (const float*)d_in[4];
    const float* bias    = (const float*)d_in[5];
    const float* gamma   = (const float*)d_in[6];
    const float* beta    = (const float*)d_in[7];
    float* out = (float*)d_out;

    char* w = (char*)d_ws;
    unsigned short* xa = (unsigned short*)w; w += (size_t)GN * 144 * 2;
    unsigned short* xb = (unsigned short*)w; w += (size_t)GN * 144 * 2;
    unsigned* cand = (unsigned*)w;           w += (size_t)GN * 128 * 4;
    float2* ew  = (float2*)w; w += (size_t)GN * GK * 8;
    unsigned short* Wth = (unsigned short*)w; w += (size_t)256 * 128 * 2;
    unsigned short* Wtl = (unsigned short*)w; w += (size_t)256 * 128 * 2;
    float* uvec = (float*)w; w += (size_t)4 * 128 * 4;
    float* sq   = (float*)w; w += (size_t)GN * 4;
    float* a_s  = (float*)w; w += (size_t)GN * GH * 4;
    float* a_d  = (float*)w; w += (size_t)GN * GH * 4;
    int*   fidx = (int*)w;   w += (size_t)GN * GK * 4;
    int*   cnt  = (int*)w;   w += (size_t)GN * 4;
    int*   curs = (int*)w;   w += (size_t)GN * 4;
    int*   offs = (int*)w;   w += (size_t)(GN + 1) * 4;
    int*   elst = (int*)w;   w += (size_t)GN * GK * 4;
    size_t need = (size_t)((char*)w - (char*)d_ws);
    if (ws_size < need) return;   // diagnostic guard

    k_prep<<<132 + GN / 4, 256, 0, stream>>>(W, att_src, att_dst, x, Wth, Wtl,
                                             uvec, sq, xa, xb, cnt, curs);
    k_gemm_topk<<<dim3(64, 33), 256, 0, stream>>>(xa, xb, x, uvec, cand, a_s, a_d);
    k_refine<<<GN / 4, 256, 0, stream>>>(cand, x, sq, fidx, cnt);
    k_fill<<<GN * GK / 256, 256, 0, stream>>>(cnt, offs, fidx, curs, elst, a_s, a_d, ew);
    k_out<<<GN / 16, 512, 0, stream>>>(offs, elst, ew, x, Wth, Wtl, bias, gamma, beta, out);
}

// Round 10
// 168.622 us; speedup vs baseline: 1.0322x; 1.0322x over previous
//
#include <hip/hip_runtime.h>
#include <hip/hip_bf16.h>
#include <math.h>

#define GN 8192
#define GD 128
#define GH 2
#define GK 3
#define NEG_SLOPE 0.2f
#define LN_EPS 1e-5f

using short8  = __attribute__((ext_vector_type(8)))  short;
using float16 = __attribute__((ext_vector_type(16))) float;
using f32x4   = __attribute__((ext_vector_type(4)))  float;

__device__ __forceinline__ float wred(float v) {
    #pragma unroll
    for (int o = 32; o > 0; o >>= 1) v += __shfl_xor(v, o, 64);
    return v;
}

// monotone float->uint encoding (ascending float -> ascending uint)
__device__ __forceinline__ unsigned fenc(float f) {
    unsigned b = __float_as_uint(f);
    return (b & 0x80000000u) ? ~b : (b | 0x80000000u);
}

__device__ __forceinline__ float rawbf2f(unsigned short s) {
    return __uint_as_float(((unsigned)s) << 16);
}
__device__ __forceinline__ unsigned short f2rawbf(float f) {
    __hip_bfloat16 b = __float2bfloat16(f);
    unsigned short r; __builtin_memcpy(&r, &b, 2);
    return r;
}
__device__ __forceinline__ unsigned umin2(unsigned a, unsigned b) { return a < b ? a : b; }
__device__ __forceinline__ unsigned umax2(unsigned a, unsigned b) { return a > b ? a : b; }

// FUSED pre-pass + conv (roles block-disjoint):
//   b <  128     : transpose W into MFMA-B bf16 hi/lo
//   b in [128,132): u vectors uvec[b][d] = sum_c W[d][h*128+c] * v[h][c]
//   b >= 132     : per-row conv: sq, xa=[-2x | hi(sq+512) lo], xb=[x | 1 1],
//                  cnt/curs zero-init.
__global__ void k_prep(const float* __restrict__ W, const float* __restrict__ att_src,
                       const float* __restrict__ att_dst, const float* __restrict__ x,
                       unsigned short* __restrict__ Wth, unsigned short* __restrict__ Wtl,
                       float* __restrict__ uvec, float* __restrict__ sq,
                       unsigned short* __restrict__ xa, unsigned short* __restrict__ xb,
                       int* __restrict__ cnt, int* __restrict__ curs) {
    __shared__ float vs[128];
    int b = blockIdx.x, t = threadIdx.x;
    if (b < 128) {
        int e = b * 256 + t;   // 32768
        int d = e >> 8, j = e & 255;
        int h = j >> 7, c = j & 127;
        int k = h * 128 + d;
        float w = W[e];
        unsigned short hi = f2rawbf(w);
        Wth[c * 256 + k] = hi;
        Wtl[c * 256 + k] = f2rawbf(w - rawbf2f(hi));
    } else if (b < 132) {
        int bb = b - 128;
        int h = bb & 1;
        const float* v = (bb < 2 ? att_src : att_dst) + h * 128;
        if (t < 128) vs[t] = v[t];
        __syncthreads();
        int d = t >> 1, half = t & 1;
        const float* wr = W + (size_t)d * 256 + h * 128 + half * 64;
        float s = 0.f;
        for (int c = 0; c < 64; c++) s += wr[c] * vs[half * 64 + c];
        s += __shfl_xor(s, 1, 64);
        if (half == 0) uvec[bb * 128 + d] = s;
    } else {
        int row = (b - 132) * 4 + (t >> 6);
        int lane = t & 63;
        const float* xr = x + (size_t)row * GD;
        float a0 = xr[lane], a1 = xr[lane + 64];
        float s = wred(a0 * a0 + a1 * a1);
        unsigned short* ar = xa + (size_t)row * 144;
        unsigned short* br = xb + (size_t)row * 144;
        ar[lane] = f2rawbf(-2.f * a0); ar[lane + 64] = f2rawbf(-2.f * a1);
        br[lane] = f2rawbf(a0);        br[lane + 64] = f2rawbf(a1);
        if (lane < 16) {
            unsigned short av = 0, bv = 0;
            if (lane == 0)      { av = f2rawbf(s + 512.f); bv = 0x3F80; }
            else if (lane == 1) { float hi = rawbf2f(f2rawbf(s + 512.f));
                                  av = f2rawbf(s + 512.f - hi); bv = 0x3F80; }
            ar[128 + lane] = av; br[128 + lane] = bv;
            if (lane == 0) {
                sq[row] = s;
                cnt[row] = 0; curs[row] = 0;
            }
        }
    }
}

// top-4 insert network step (order-independent, keys distinct)
#define INS(U0,U1,U2,U3,kk) do {                                   \
    unsigned m0_ = umax2(U0,(kk)); U0 = umin2(U0,(kk));            \
    unsigned m1_ = umax2(U1,m0_);  U1 = umin2(U1,m0_);             \
    unsigned m2_ = umax2(U2,m1_);  U2 = umin2(U2,m1_);             \
    U3 = umin2(U3,m2_); } while(0)

// quad-granular guarded insert of one float16 accumulator.
// A quad whose masked min > U3 cannot change U0..U3 -> skipping is bit-exact.
#define TOPK16(A, U0,U1,U2,U3, rbase) do {                                        \
    _Pragma("unroll")                                                             \
    for (int q4_ = 0; q4_ < 4; q4_++) {                                           \
        unsigned c0_ = __float_as_uint((A)[q4_ * 4 + 0]);                         \
        unsigned c1_ = __float_as_uint((A)[q4_ * 4 + 1]);                         \
        unsigned c2_ = __float_as_uint((A)[q4_ * 4 + 2]);                         \
        unsigned c3_ = __float_as_uint((A)[q4_ * 4 + 3]);                         \
        unsigned qm_ = umin2(umin2(c0_, c1_), umin2(c2_, c3_));                   \
        if ((qm_ & 0xFFFFE000u) <= U3) {                                          \
            INS(U0,U1,U2,U3, (c0_ & 0xFFFFE000u) | (unsigned)((rbase) + 0 + 8 * q4_)); \
            INS(U0,U1,U2,U3, (c1_ & 0xFFFFE000u) | (unsigned)((rbase) + 1 + 8 * q4_)); \
            INS(U0,U1,U2,U3, (c2_ & 0xFFFFE000u) | (unsigned)((rbase) + 2 + 8 * q4_)); \
            INS(U0,U1,U2,U3, (c3_ & 0xFFFFE000u) | (unsigned)((rbase) + 3 + 8 * q4_)); \
        }                                                                         \
    } } while(0)

// MFMA candidate kNN. score'_ij = 512 + sq_i - 2 x_i.x_j (> 0 -> raw bits monotone).
// grid (64,32): 128 cols x one 256-row superblock per block; top-4/superblock/col
// -> 128 keys per col. 32-row half-tiles double-buffered in 2x9 KB LDS;
// __launch_bounds__(256,8) -> 8 blocks/CU co-resident (32 waves/CU, HW max;
// 144 KB LDS/CU; VGPR cap 64, measured use 40).
#define STAGE_HALF(buf, rowbase)                                                  \
    do {                                                                          \
        _Pragma("unroll")                                                         \
        for (int s_ = 0; s_ < 3; s_++) {                                          \
            if (s_ < 2 || t < 64) {                                               \
                int q_ = s_ * 256 + t;     /* 0..575: 18 chunks x 32 rows */      \
                int kb_ = q_ >> 5, r_ = q_ & 31;                                  \
                __builtin_amdgcn_global_load_lds(                                 \
                    (const __attribute__((address_space(1))) unsigned*)           \
                        (xa + (size_t)((rowbase) + r_) * 144 + kb_ * 8),          \
                    (__attribute__((address_space(3))) unsigned*)&At[(buf)][q_ * 8],\
                    16, 0, 0);                                                    \
            }                                                                     \
        }                                                                         \
    } while (0)

__launch_bounds__(256, 8)
__global__ void k_gemm_topk(const unsigned short* __restrict__ xa,
                            const unsigned short* __restrict__ xb,
                            unsigned* __restrict__ cand) {
    __shared__ __align__(16) unsigned short At[2][18 * 32 * 8];  // 2 x 9 KB
    int t = threadIdx.x;
    int w = t >> 6, lane = t & 63, h = lane >> 5, n = lane & 31;
    int col = blockIdx.x * 128 + w * 32 + n;
    int sb = blockIdx.y;                 // 0..31, 256-row superblock
    int rb0 = sb * 256;

    short8 bfrag[9];
    #pragma unroll
    for (int kc = 0; kc < 9; kc++)
        bfrag[kc] = *(const short8*)(xb + (size_t)col * 144 + (2 * kc + h) * 8);

    STAGE_HALF(0, rb0);
    asm volatile("s_waitcnt vmcnt(0)" ::: "memory");
    __builtin_amdgcn_s_barrier();

    unsigned T0 = 0xFFFFFFFFu, T1 = 0xFFFFFFFFu, T2 = 0xFFFFFFFFu, T3 = 0xFFFFFFFFu;

    #pragma unroll 1
    for (int ht = 0; ht < 8; ht++) {
        int cur = ht & 1;
        if (ht < 7) STAGE_HALF(cur ^ 1, rb0 + (ht + 1) * 32);

        float16 acc = (float16)(0.f);

        #pragma unroll
        for (int kc = 0; kc < 9; kc++) {
            short8 a = *(const short8*)&At[cur][(((2 * kc + h) * 32) + n) * 8];
            acc = __builtin_amdgcn_mfma_f32_32x32x16_bf16(a, bfrag[kc], acc, 0, 0, 0);
        }

        int rbq = rb0 + ht * 32 + 4 * h;
        TOPK16(acc, T0, T1, T2, T3, rbq);

        if (ht < 7) {
            asm volatile("s_waitcnt vmcnt(0)" ::: "memory");
            __builtin_amdgcn_s_barrier();
        }
    }

    // merge the two 32-row halves (h=0/1) of each column, write top-4
    unsigned p0 = (unsigned)__shfl_xor((int)T0, 32), p1 = (unsigned)__shfl_xor((int)T1, 32),
             p2 = (unsigned)__shfl_xor((int)T2, 32), p3 = (unsigned)__shfl_xor((int)T3, 32);
    INS(T0,T1,T2,T3, p0); INS(T0,T1,T2,T3, p1);
    INS(T0,T1,T2,T3, p2); INS(T0,T1,T2,T3, p3);
    if (h == 0) {
        uint4 o = make_uint4(T0, T1, T2, T3);
        *(uint4*)(cand + (size_t)col * 128 + sb * 4) = o;
    }
}

__device__ __forceinline__ int clampN(int v) {
    return v < 0 ? 0 : (v >= GN ? GN - 1 : v);
}

// two-stage refine (blocks < 2048), one wave per node; PLUS a_s/a_d tail
// (blocks >= 2048): one row per wave, fully parallel (8192 waves) — hidden
// under the refine blocks, unlike a serial per-wave loop.
__global__ void k_refine(const unsigned* __restrict__ cand,
                         const float* __restrict__ x, const float* __restrict__ sq,
                         const float* __restrict__ uvec,
                         int* __restrict__ fidx, int* __restrict__ cnt,
                         float* __restrict__ a_s, float* __restrict__ a_d) {
    int t = threadIdx.x, wv = t >> 6, lane = t & 63;

    if (blockIdx.x >= 2048) {
        int row = (blockIdx.x - 2048) * 4 + wv;
        const float* xr = x + (size_t)row * GD;
        float a0 = xr[lane], a1 = xr[lane + 64];
        float s0 = wred(a0 * uvec[lane]       + a1 * uvec[64 + lane]);
        float s1 = wred(a0 * uvec[128 + lane] + a1 * uvec[192 + lane]);
        float d0 = wred(a0 * uvec[256 + lane] + a1 * uvec[320 + lane]);
        float d1 = wred(a0 * uvec[384 + lane] + a1 * uvec[448 + lane]);
        if (lane == 0) {
            a_s[row * 2] = s0; a_s[row * 2 + 1] = s1;
            a_d[row * 2] = d0; a_d[row * 2 + 1] = d1;
        }
        return;
    }

    int j = blockIdx.x * 4 + wv;
    int c = lane >> 2, g = lane & 3;

    unsigned k0 = cand[(size_t)j * 128 + lane];
    unsigned k1 = cand[(size_t)j * 128 + 64 + lane];
    int myidx = 0;
    #pragma unroll
    for (int r = 0; r < 16; r++) {
        unsigned m = umin2(k0, k1);
        #pragma unroll
        for (int o = 32; o > 0; o >>= 1)
            m = umin2(m, (unsigned)__shfl_xor((int)m, o, 64));
        myidx = (c == r) ? (int)(m & 8191u) : myidx;
        k0 = (k0 == m) ? 0xFFFFFFFFu : k0;
        k1 = (k1 == m) ? 0xFFFFFFFFu : k1;
    }

    const float* xi = x + (size_t)myidx * GD + g * 32;
    const float* xj = x + (size_t)j * GD + g * 32;
    float p = 0.f;
    #pragma unroll
    for (int d4 = 0; d4 < 8; d4++) {
        float4 a = *(const float4*)(xi + d4 * 4);
        float4 b = *(const float4*)(xj + d4 * 4);
        p += a.x * b.x + a.y * b.y + a.z * b.z + a.w * b.w;
    }
    p += __shfl_xor(p, 1, 64);
    p += __shfl_xor(p, 2, 64);
    float d2 = sq[j] + sq[myidx] - 2.f * p;
    unsigned long long key = ((unsigned long long)fenc(d2) << 32) | (unsigned)myidx;

    int out3[3];
    #pragma unroll
    for (int r = 0; r < 3; r++) {
        unsigned long long k = key;
        #pragma unroll
        for (int o = 4; o <= 32; o <<= 1) {
            unsigned long long other = __shfl_xor(k, o, 64);
            k = k < other ? k : other;
        }
        out3[r] = (int)(unsigned)(k & 8191u);
        key = (key == k) ? ~0ull : key;   // group keys removed together (idx unique)
    }
    if (lane == 0) {
        int i0 = clampN(out3[0]), i1 = clampN(out3[1]), i2 = clampN(out3[2]);
        fidx[j * 3 + 0] = i0; fidx[j * 3 + 1] = i1; fidx[j * 3 + 2] = i2;
        atomicAdd(&cnt[i0], 1); atomicAdd(&cnt[i1], 1); atomicAdd(&cnt[i2], 1);
    }
}

// FUSED scan + fill: every block redundantly computes the full 8192 prefix
// scan of cnt (deterministic integer scan -> identical in all blocks; 32 KB
// L2-hot), keeps it in LDS, and block 0 additionally writes global offs for
// k_out. Then the per-edge CSR scatter proceeds against the LDS offsets.
__global__ void k_fill(const int* __restrict__ cnt, int* __restrict__ offs,
                       const int* __restrict__ fidx,
                       int* __restrict__ cursor, int* __restrict__ elist,
                       const float* __restrict__ a_s, const float* __restrict__ a_d,
                       float2* __restrict__ ew) {
    __shared__ __align__(16) int buf[8192];
    __shared__ int wtot[4];
    int t = threadIdx.x, wv = t >> 6, lane = t & 63;

    #pragma unroll
    for (int j = 0; j < 8; j++)
        ((int4*)buf)[j * 256 + t] = ((const int4*)cnt)[j * 256 + t];
    __syncthreads();
    int loc[32], s = 0;
    #pragma unroll
    for (int k = 0; k < 32; k++) { loc[k] = s; s += buf[t * 32 + k]; }
    int inc = s;
    #pragma unroll
    for (int d = 1; d < 64; d <<= 1) {
        int nv = __shfl_up(inc, d, 64);
        if (lane >= d) inc += nv;
    }
    if (lane == 63) wtot[wv] = inc;
    __syncthreads();
    int wbase = 0;
    #pragma unroll
    for (int wq = 0; wq < 4; wq++) wbase += (wq < wv) ? wtot[wq] : 0;
    int base = wbase + inc - s;
    #pragma unroll
    for (int k = 0; k < 32; k++) buf[t * 32 + k] = base + loc[k];
    __syncthreads();
    if (blockIdx.x == 0) {
        #pragma unroll
        for (int j = 0; j < 8; j++)
            ((int4*)offs)[j * 256 + t] = ((int4*)buf)[j * 256 + t];
        if (t == 255) offs[GN] = wtot[0] + wtot[1] + wtot[2] + wtot[3];
    }

    int eid = blockIdx.x * 256 + t;
    int i = clampN(fidx[eid]);
    int src = eid / 3;
    float2 as = ((const float2*)a_s)[src];
    float2 ad = ((const float2*)a_d)[i];
    float e0 = as.x + ad.x; e0 = e0 >= 0.f ? e0 : NEG_SLOPE * e0;
    float e1 = as.y + ad.y; e1 = e1 >= 0.f ? e1 : NEG_SLOPE * e1;
    float w0 = expf(e0), w1 = expf(e1);
    int pos = atomicAdd(&cursor[i], 1);
    int slot = buf[i] + pos;
    if (slot < GN * GK) { elist[slot] = src; ew[slot] = make_float2(w0, w1); }
}

// fused aggregation: 16 nodes/block, 512 threads (8 waves; 2 nodes/wave).
__launch_bounds__(512, 4)
__global__ void k_out(const int* __restrict__ offs, const int* __restrict__ elst,
                      const float2* __restrict__ ew,
                      const float* __restrict__ x,
                      const unsigned short* __restrict__ Wth,
                      const unsigned short* __restrict__ Wtl,
                      const float* __restrict__ bias, const float* __restrict__ gamma,
                      const float* __restrict__ beta, float* __restrict__ out) {
    __shared__ unsigned short zh[16][264];
    __shared__ unsigned short zl[16][264];
    __shared__ float os[16][132];
    int t = threadIdx.x, i0 = blockIdx.x * 16;
    int wv = t >> 6, lane = t & 63;
    int eslot = lane >> 3, g = lane & 7;

    #pragma unroll
    for (int pp = 0; pp < 2; pp++) {
        int r = wv * 2 + pp, node = i0 + r;
        int s = offs[node], e = offs[node + 1];
        float acc0[16], acc1[16];
        #pragma unroll
        for (int q = 0; q < 16; q++) { acc0[q] = 0.f; acc1[q] = 0.f; }
        float w0s = 0.f, w1s = 0.f;
        for (int k0 = s; k0 < e; k0 += 8) {
            int k = k0 + eslot;
            bool valid = k < e;
            int j = valid ? elst[k] : 0;
            float2 wv2 = valid ? ew[k] : make_float2(0.f, 0.f);
            const float* xr = x + (size_t)j * GD + g * 16;
            float4 x0 = *(const float4*)(xr);
            float4 x1 = *(const float4*)(xr + 4);
            float4 x2 = *(const float4*)(xr + 8);
            float4 x3 = *(const float4*)(xr + 12);
            float xv[16] = {x0.x, x0.y, x0.z, x0.w, x1.x, x1.y, x1.z, x1.w,
                            x2.x, x2.y, x2.z, x2.w, x3.x, x3.y, x3.z, x3.w};
            #pragma unroll
            for (int q = 0; q < 16; q++) {
                acc0[q] += wv2.x * xv[q];
                acc1[q] += wv2.y * xv[q];
            }
            w0s += wv2.x; w1s += wv2.y;
        }
        #pragma unroll
        for (int m = 8; m <= 32; m <<= 1) {
            #pragma unroll
            for (int q = 0; q < 16; q++) {
                acc0[q] += __shfl_xor(acc0[q], m, 64);
                acc1[q] += __shfl_xor(acc1[q], m, 64);
            }
            w0s += __shfl_xor(w0s, m, 64);
            w1s += __shfl_xor(w1s, m, 64);
        }
        if (lane < 8) {
            float dn0 = 0.5f / w0s, dn1 = 0.5f / w1s;
            #pragma unroll
            for (int q = 0; q < 16; q += 2) {
                float a0 = acc0[q] * dn0, a1 = acc0[q + 1] * dn0;
                unsigned short h0 = f2rawbf(a0), h1 = f2rawbf(a1);
                *(unsigned*)&zh[r][lane * 16 + q] = (unsigned)h0 | ((unsigned)h1 << 16);
                *(unsigned*)&zl[r][lane * 16 + q] =
                    (unsigned)f2rawbf(a0 - rawbf2f(h0)) |
                    ((unsigned)f2rawbf(a1 - rawbf2f(h1)) << 16);
                float b0 = acc1[q] * dn1, b1 = acc1[q + 1] * dn1;
                unsigned short p0 = f2rawbf(b0), p1 = f2rawbf(b1);
                *(unsigned*)&zh[r][128 + lane * 16 + q] = (unsigned)p0 | ((unsigned)p1 << 16);
                *(unsigned*)&zl[r][128 + lane * 16 + q] =
                    (unsigned)f2rawbf(b0 - rawbf2f(p0)) |
                    ((unsigned)f2rawbf(b1 - rawbf2f(p1)) << 16);
            }
        }
    }
    __syncthreads();

    {
        int qd = lane >> 4, an = lane & 15;
        int c = wv * 16 + an;
        f32x4 acc = {0.f, 0.f, 0.f, 0.f};
        #pragma unroll
        for (int s = 0; s < 8; s++) {
            int ko = s * 32 + qd * 8;
            short8 ah = *(const short8*)&zh[an][ko];
            short8 al = *(const short8*)&zl[an][ko];
            short8 bh = *(const short8*)(Wth + (size_t)c * 256 + ko);
            short8 bl = *(const short8*)(Wtl + (size_t)c * 256 + ko);
            acc = __builtin_amdgcn_mfma_f32_16x16x32_bf16(ah, bh, acc, 0, 0, 0);
            acc = __builtin_amdgcn_mfma_f32_16x16x32_bf16(al, bh, acc, 0, 0, 0);
            acc = __builtin_amdgcn_mfma_f32_16x16x32_bf16(ah, bl, acc, 0, 0, 0);
        }
        #pragma unroll
        for (int r = 0; r < 4; r++) os[qd * 4 + r][c] = acc[r];
    }
    __syncthreads();

    #pragma unroll
    for (int pp = 0; pp < 2; pp++) {
        int r = wv * 2 + pp, node = i0 + r;
        float y0 = os[r][lane] + bias[lane];
        float y1 = os[r][lane + 64] + bias[lane + 64];
        float mu = wred(y0 + y1) * (1.f / 128.f);
        float c0 = y0 - mu, c1 = y1 - mu;
        float var = wred(c0 * c0 + c1 * c1) * (1.f / 128.f);
        float rs2 = 1.f / sqrtf(var + LN_EPS);
        float n0 = c0 * rs2 * gamma[lane] + beta[lane];
        float n1 = c1 * rs2 * gamma[lane + 64] + beta[lane + 64];
        n0 = n0 > 0.f ? n0 : 0.f;
        n1 = n1 > 0.f ? n1 : 0.f;
        out[(size_t)node * GD + lane]      = x[(size_t)node * GD + lane] + n0;
        out[(size_t)node * GD + lane + 64] = x[(size_t)node * GD + lane + 64] + n1;
    }
}

extern "C" void kernel_launch(void* const* d_in, const int* in_sizes, int n_in,
                              void* d_out, int out_size, void* d_ws, size_t ws_size,
                              hipStream_t stream) {
    const float* x       = (const float*)d_in[0];
    const float* W       = (const float*)d_in[2];
    const float* att_src = (const float*)d_in[3];
    const float* att_dst = (const float*)d_in[4];
    const float* bias    = (const float*)d_in[5];
    const float* gamma   = (const float*)d_in[6];
    const float* beta    = (const float*)d_in[7];
    float* out = (float*)d_out;

    char* w = (char*)d_ws;
    unsigned short* xa = (unsigned short*)w; w += (size_t)GN * 144 * 2;
    unsigned short* xb = (unsigned short*)w; w += (size_t)GN * 144 * 2;
    unsigned* cand = (unsigned*)w;           w += (size_t)GN * 128 * 4;
    float2* ew  = (float2*)w; w += (size_t)GN * GK * 8;
    unsigned short* Wth = (unsigned short*)w; w += (size_t)256 * 128 * 2;
    unsigned short* Wtl = (unsigned short*)w; w += (size_t)256 * 128 * 2;
    float* uvec = (float*)w; w += (size_t)4 * 128 * 4;
    float* sq   = (float*)w; w += (size_t)GN * 4;
    float* a_s  = (float*)w; w += (size_t)GN * GH * 4;
    float* a_d  = (float*)w; w += (size_t)GN * GH * 4;
    int*   fidx = (int*)w;   w += (size_t)GN * GK * 4;
    int*   cnt  = (int*)w;   w += (size_t)GN * 4;
    int*   curs = (int*)w;   w += (size_t)GN * 4;
    int*   offs = (int*)w;   w += (size_t)(GN + 1) * 4;
    int*   elst = (int*)w;   w += (size_t)GN * GK * 4;
    size_t need = (size_t)((char*)w - (char*)d_ws);
    if (ws_size < need) return;   // diagnostic guard

    k_prep<<<132 + GN / 4, 256, 0, stream>>>(W, att_src, att_dst, x, Wth, Wtl,
                                             uvec, sq, xa, xb, cnt, curs);
    k_gemm_topk<<<dim3(64, 32), 256, 0, stream>>>(xa, xb, cand);
    k_refine<<<GN / 4 + GN / 4, 256, 0, stream>>>(cand, x, sq, uvec, fidx, cnt, a_s, a_d);
    k_fill<<<GN * GK / 256, 256, 0, stream>>>(cnt, offs, fidx, curs, elst, a_s, a_d, ew);
    k_out<<<GN / 16, 512, 0, stream>>>(offs, elst, ew, x, Wth, Wtl, bias, gamma, beta, out);
}

// Round 11
// 158.859 us; speedup vs baseline: 1.0957x; 1.0615x over previous
//
#include <hip/hip_runtime.h>
#include <hip/hip_bf16.h>
#include <math.h>

#define GN 8192
#define GD 128
#define GH 2
#define GK 3
#define NEG_SLOPE 0.2f
#define LN_EPS 1e-5f

using short8  = __attribute__((ext_vector_type(8)))  short;
using float16 = __attribute__((ext_vector_type(16))) float;
using f32x4   = __attribute__((ext_vector_type(4)))  float;

__device__ __forceinline__ float wred(float v) {
    #pragma unroll
    for (int o = 32; o > 0; o >>= 1) v += __shfl_xor(v, o, 64);
    return v;
}

// monotone float->uint encoding (ascending float -> ascending uint)
__device__ __forceinline__ unsigned fenc(float f) {
    unsigned b = __float_as_uint(f);
    return (b & 0x80000000u) ? ~b : (b | 0x80000000u);
}

__device__ __forceinline__ float rawbf2f(unsigned short s) {
    return __uint_as_float(((unsigned)s) << 16);
}
__device__ __forceinline__ unsigned short f2rawbf(float f) {
    __hip_bfloat16 b = __float2bfloat16(f);
    unsigned short r; __builtin_memcpy(&r, &b, 2);
    return r;
}
__device__ __forceinline__ unsigned umin2(unsigned a, unsigned b) { return a < b ? a : b; }
__device__ __forceinline__ unsigned umax2(unsigned a, unsigned b) { return a > b ? a : b; }

// FUSED pre-pass + conv (roles block-disjoint):
//   b <  128     : transpose W into MFMA-B bf16 hi/lo
//   b in [128,132): u vectors uvec[b][d] = sum_c W[d][h*128+c] * v[h][c]
//   b >= 132     : per-row conv: sq, xa=[-2x | hi(sq+512) lo], xb=[x | 1 1],
//                  cnt/curs zero-init.
__global__ void k_prep(const float* __restrict__ W, const float* __restrict__ att_src,
                       const float* __restrict__ att_dst, const float* __restrict__ x,
                       unsigned short* __restrict__ Wth, unsigned short* __restrict__ Wtl,
                       float* __restrict__ uvec, float* __restrict__ sq,
                       unsigned short* __restrict__ xa, unsigned short* __restrict__ xb,
                       int* __restrict__ cnt, int* __restrict__ curs) {
    __shared__ float vs[128];
    int b = blockIdx.x, t = threadIdx.x;
    if (b < 128) {
        int e = b * 256 + t;   // 32768
        int d = e >> 8, j = e & 255;
        int h = j >> 7, c = j & 127;
        int k = h * 128 + d;
        float w = W[e];
        unsigned short hi = f2rawbf(w);
        Wth[c * 256 + k] = hi;
        Wtl[c * 256 + k] = f2rawbf(w - rawbf2f(hi));
    } else if (b < 132) {
        int bb = b - 128;
        int h = bb & 1;
        const float* v = (bb < 2 ? att_src : att_dst) + h * 128;
        if (t < 128) vs[t] = v[t];
        __syncthreads();
        int d = t >> 1, half = t & 1;
        const float* wr = W + (size_t)d * 256 + h * 128 + half * 64;
        float s = 0.f;
        for (int c = 0; c < 64; c++) s += wr[c] * vs[half * 64 + c];
        s += __shfl_xor(s, 1, 64);
        if (half == 0) uvec[bb * 128 + d] = s;
    } else {
        int row = (b - 132) * 4 + (t >> 6);
        int lane = t & 63;
        const float* xr = x + (size_t)row * GD;
        float a0 = xr[lane], a1 = xr[lane + 64];
        float s = wred(a0 * a0 + a1 * a1);
        unsigned short* ar = xa + (size_t)row * 144;
        unsigned short* br = xb + (size_t)row * 144;
        ar[lane] = f2rawbf(-2.f * a0); ar[lane + 64] = f2rawbf(-2.f * a1);
        br[lane] = f2rawbf(a0);        br[lane + 64] = f2rawbf(a1);
        if (lane < 16) {
            unsigned short av = 0, bv = 0;
            if (lane == 0)      { av = f2rawbf(s + 512.f); bv = 0x3F80; }
            else if (lane == 1) { float hi = rawbf2f(f2rawbf(s + 512.f));
                                  av = f2rawbf(s + 512.f - hi); bv = 0x3F80; }
            ar[128 + lane] = av; br[128 + lane] = bv;
            if (lane == 0) {
                sq[row] = s;
                cnt[row] = 0; curs[row] = 0;
            }
        }
    }
}

// top-4 insert network step (order-independent, keys distinct)
#define INS(U0,U1,U2,U3,kk) do {                                   \
    unsigned m0_ = umax2(U0,(kk)); U0 = umin2(U0,(kk));            \
    unsigned m1_ = umax2(U1,m0_);  U1 = umin2(U1,m0_);             \
    unsigned m2_ = umax2(U2,m1_);  U2 = umin2(U2,m1_);             \
    U3 = umin2(U3,m2_); } while(0)

// quad-granular guarded insert of one float16 accumulator.
// A quad whose masked min > U3 cannot change U0..U3 -> skipping is bit-exact.
#define TOPK16(A, U0,U1,U2,U3, rbase) do {                                        \
    _Pragma("unroll")                                                             \
    for (int q4_ = 0; q4_ < 4; q4_++) {                                           \
        unsigned c0_ = __float_as_uint((A)[q4_ * 4 + 0]);                         \
        unsigned c1_ = __float_as_uint((A)[q4_ * 4 + 1]);                         \
        unsigned c2_ = __float_as_uint((A)[q4_ * 4 + 2]);                         \
        unsigned c3_ = __float_as_uint((A)[q4_ * 4 + 3]);                         \
        unsigned qm_ = umin2(umin2(c0_, c1_), umin2(c2_, c3_));                   \
        if ((qm_ & 0xFFFFE000u) <= U3) {                                          \
            INS(U0,U1,U2,U3, (c0_ & 0xFFFFE000u) | (unsigned)((rbase) + 0 + 8 * q4_)); \
            INS(U0,U1,U2,U3, (c1_ & 0xFFFFE000u) | (unsigned)((rbase) + 1 + 8 * q4_)); \
            INS(U0,U1,U2,U3, (c2_ & 0xFFFFE000u) | (unsigned)((rbase) + 2 + 8 * q4_)); \
            INS(U0,U1,U2,U3, (c3_ & 0xFFFFE000u) | (unsigned)((rbase) + 3 + 8 * q4_)); \
        }                                                                         \
    } } while(0)

// MFMA candidate kNN. score'_ij = 512 + sq_i - 2 x_i.x_j (> 0 -> raw bits monotone).
// grid (64,32): 128 cols x one 256-row superblock per block; top-4/superblock/col
// -> 128 keys per col. 32-row half-tiles double-buffered in 2x9 KB LDS;
// __launch_bounds__(256,6) -> 6 blocks/CU co-resident (24 waves/CU).
// (256,8) tested R10: compiler caps VGPR at 32 -> spill, WRITE_SIZE 4->26 MB,
// net regression. (256,6) w/ VGPR=40 is the verified optimum of this family.
#define STAGE_HALF(buf, rowbase)                                                  \
    do {                                                                          \
        _Pragma("unroll")                                                         \
        for (int s_ = 0; s_ < 3; s_++) {                                          \
            if (s_ < 2 || t < 64) {                                               \
                int q_ = s_ * 256 + t;     /* 0..575: 18 chunks x 32 rows */      \
                int kb_ = q_ >> 5, r_ = q_ & 31;                                  \
                __builtin_amdgcn_global_load_lds(                                 \
                    (const __attribute__((address_space(1))) unsigned*)           \
                        (xa + (size_t)((rowbase) + r_) * 144 + kb_ * 8),          \
                    (__attribute__((address_space(3))) unsigned*)&At[(buf)][q_ * 8],\
                    16, 0, 0);                                                    \
            }                                                                     \
        }                                                                         \
    } while (0)

__launch_bounds__(256, 6)
__global__ void k_gemm_topk(const unsigned short* __restrict__ xa,
                            const unsigned short* __restrict__ xb,
                            unsigned* __restrict__ cand) {
    __shared__ __align__(16) unsigned short At[2][18 * 32 * 8];  // 2 x 9 KB
    int t = threadIdx.x;
    int w = t >> 6, lane = t & 63, h = lane >> 5, n = lane & 31;
    int col = blockIdx.x * 128 + w * 32 + n;
    int sb = blockIdx.y;                 // 0..31, 256-row superblock
    int rb0 = sb * 256;

    short8 bfrag[9];
    #pragma unroll
    for (int kc = 0; kc < 9; kc++)
        bfrag[kc] = *(const short8*)(xb + (size_t)col * 144 + (2 * kc + h) * 8);

    STAGE_HALF(0, rb0);
    asm volatile("s_waitcnt vmcnt(0)" ::: "memory");
    __builtin_amdgcn_s_barrier();

    unsigned T0 = 0xFFFFFFFFu, T1 = 0xFFFFFFFFu, T2 = 0xFFFFFFFFu, T3 = 0xFFFFFFFFu;

    #pragma unroll 1
    for (int ht = 0; ht < 8; ht++) {
        int cur = ht & 1;
        if (ht < 7) STAGE_HALF(cur ^ 1, rb0 + (ht + 1) * 32);

        float16 acc = (float16)(0.f);

        #pragma unroll
        for (int kc = 0; kc < 9; kc++) {
            short8 a = *(const short8*)&At[cur][(((2 * kc + h) * 32) + n) * 8];
            acc = __builtin_amdgcn_mfma_f32_32x32x16_bf16(a, bfrag[kc], acc, 0, 0, 0);
        }

        int rbq = rb0 + ht * 32 + 4 * h;
        TOPK16(acc, T0, T1, T2, T3, rbq);

        if (ht < 7) {
            asm volatile("s_waitcnt vmcnt(0)" ::: "memory");
            __builtin_amdgcn_s_barrier();
        }
    }

    // merge the two 32-row halves (h=0/1) of each column, write top-4
    unsigned p0 = (unsigned)__shfl_xor((int)T0, 32), p1 = (unsigned)__shfl_xor((int)T1, 32),
             p2 = (unsigned)__shfl_xor((int)T2, 32), p3 = (unsigned)__shfl_xor((int)T3, 32);
    INS(T0,T1,T2,T3, p0); INS(T0,T1,T2,T3, p1);
    INS(T0,T1,T2,T3, p2); INS(T0,T1,T2,T3, p3);
    if (h == 0) {
        uint4 o = make_uint4(T0, T1, T2, T3);
        *(uint4*)(cand + (size_t)col * 128 + sb * 4) = o;
    }
}

__device__ __forceinline__ int clampN(int v) {
    return v < 0 ? 0 : (v >= GN ? GN - 1 : v);
}

// two-stage refine (blocks < 2048), one wave per node; PLUS a_s/a_d tail
// (blocks >= 2048): one row per wave, fully parallel (8192 waves) — hidden
// under the refine blocks.
__global__ void k_refine(const unsigned* __restrict__ cand,
                         const float* __restrict__ x, const float* __restrict__ sq,
                         const float* __restrict__ uvec,
                         int* __restrict__ fidx, int* __restrict__ cnt,
                         float* __restrict__ a_s, float* __restrict__ a_d) {
    int t = threadIdx.x, wv = t >> 6, lane = t & 63;

    if (blockIdx.x >= 2048) {
        int row = (blockIdx.x - 2048) * 4 + wv;
        const float* xr = x + (size_t)row * GD;
        float a0 = xr[lane], a1 = xr[lane + 64];
        float s0 = wred(a0 * uvec[lane]       + a1 * uvec[64 + lane]);
        float s1 = wred(a0 * uvec[128 + lane] + a1 * uvec[192 + lane]);
        float d0 = wred(a0 * uvec[256 + lane] + a1 * uvec[320 + lane]);
        float d1 = wred(a0 * uvec[384 + lane] + a1 * uvec[448 + lane]);
        if (lane == 0) {
            a_s[row * 2] = s0; a_s[row * 2 + 1] = s1;
            a_d[row * 2] = d0; a_d[row * 2 + 1] = d1;
        }
        return;
    }

    int j = blockIdx.x * 4 + wv;
    int c = lane >> 2, g = lane & 3;

    unsigned k0 = cand[(size_t)j * 128 + lane];
    unsigned k1 = cand[(size_t)j * 128 + 64 + lane];
    int myidx = 0;
    #pragma unroll
    for (int r = 0; r < 16; r++) {
        unsigned m = umin2(k0, k1);
        #pragma unroll
        for (int o = 32; o > 0; o >>= 1)
            m = umin2(m, (unsigned)__shfl_xor((int)m, o, 64));
        myidx = (c == r) ? (int)(m & 8191u) : myidx;
        k0 = (k0 == m) ? 0xFFFFFFFFu : k0;
        k1 = (k1 == m) ? 0xFFFFFFFFu : k1;
    }

    const float* xi = x + (size_t)myidx * GD + g * 32;
    const float* xj = x + (size_t)j * GD + g * 32;
    float p = 0.f;
    #pragma unroll
    for (int d4 = 0; d4 < 8; d4++) {
        float4 a = *(const float4*)(xi + d4 * 4);
        float4 b = *(const float4*)(xj + d4 * 4);
        p += a.x * b.x + a.y * b.y + a.z * b.z + a.w * b.w;
    }
    p += __shfl_xor(p, 1, 64);
    p += __shfl_xor(p, 2, 64);
    float d2 = sq[j] + sq[myidx] - 2.f * p;
    unsigned long long key = ((unsigned long long)fenc(d2) << 32) | (unsigned)myidx;

    int out3[3];
    #pragma unroll
    for (int r = 0; r < 3; r++) {
        unsigned long long k = key;
        #pragma unroll
        for (int o = 4; o <= 32; o <<= 1) {
            unsigned long long other = __shfl_xor(k, o, 64);
            k = k < other ? k : other;
        }
        out3[r] = (int)(unsigned)(k & 8191u);
        key = (key == k) ? ~0ull : key;   // group keys removed together (idx unique)
    }
    if (lane == 0) {
        int i0 = clampN(out3[0]), i1 = clampN(out3[1]), i2 = clampN(out3[2]);
        fidx[j * 3 + 0] = i0; fidx[j * 3 + 1] = i1; fidx[j * 3 + 2] = i2;
        atomicAdd(&cnt[i0], 1); atomicAdd(&cnt[i1], 1); atomicAdd(&cnt[i2], 1);
    }
}

// FUSED scan + fill: every block redundantly computes the full 8192 prefix
// scan of cnt (deterministic integer scan -> identical in all blocks; 32 KB
// L2-hot), keeps it in LDS, and block 0 additionally writes global offs for
// k_out. Then the per-edge CSR scatter proceeds against the LDS offsets.
__global__ void k_fill(const int* __restrict__ cnt, int* __restrict__ offs,
                       const int* __restrict__ fidx,
                       int* __restrict__ cursor, int* __restrict__ elist,
                       const float* __restrict__ a_s, const float* __restrict__ a_d,
                       float2* __restrict__ ew) {
    __shared__ __align__(16) int buf[8192];
    __shared__ int wtot[4];
    int t = threadIdx.x, wv = t >> 6, lane = t & 63;

    #pragma unroll
    for (int j = 0; j < 8; j++)
        ((int4*)buf)[j * 256 + t] = ((const int4*)cnt)[j * 256 + t];
    __syncthreads();
    int loc[32], s = 0;
    #pragma unroll
    for (int k = 0; k < 32; k++) { loc[k] = s; s += buf[t * 32 + k]; }
    int inc = s;
    #pragma unroll
    for (int d = 1; d < 64; d <<= 1) {
        int nv = __shfl_up(inc, d, 64);
        if (lane >= d) inc += nv;
    }
    if (lane == 63) wtot[wv] = inc;
    __syncthreads();
    int wbase = 0;
    #pragma unroll
    for (int wq = 0; wq < 4; wq++) wbase += (wq < wv) ? wtot[wq] : 0;
    int base = wbase + inc - s;
    #pragma unroll
    for (int k = 0; k < 32; k++) buf[t * 32 + k] = base + loc[k];
    __syncthreads();
    if (blockIdx.x == 0) {
        #pragma unroll
        for (int j = 0; j < 8; j++)
            ((int4*)offs)[j * 256 + t] = ((int4*)buf)[j * 256 + t];
        if (t == 255) offs[GN] = wtot[0] + wtot[1] + wtot[2] + wtot[3];
    }

    int eid = blockIdx.x * 256 + t;
    int i = clampN(fidx[eid]);
    int src = eid / 3;
    float2 as = ((const float2*)a_s)[src];
    float2 ad = ((const float2*)a_d)[i];
    float e0 = as.x + ad.x; e0 = e0 >= 0.f ? e0 : NEG_SLOPE * e0;
    float e1 = as.y + ad.y; e1 = e1 >= 0.f ? e1 : NEG_SLOPE * e1;
    float w0 = expf(e0), w1 = expf(e1);
    int pos = atomicAdd(&cursor[i], 1);
    int slot = buf[i] + pos;
    if (slot < GN * GK) { elist[slot] = src; ew[slot] = make_float2(w0, w1); }
}

// fused aggregation: 16 nodes/block, 512 threads (8 waves; 2 nodes/wave).
__launch_bounds__(512, 4)
__global__ void k_out(const int* __restrict__ offs, const int* __restrict__ elst,
                      const float2* __restrict__ ew,
                      const float* __restrict__ x,
                      const unsigned short* __restrict__ Wth,
                      const unsigned short* __restrict__ Wtl,
                      const float* __restrict__ bias, const float* __restrict__ gamma,
                      const float* __restrict__ beta, float* __restrict__ out) {
    __shared__ unsigned short zh[16][264];
    __shared__ unsigned short zl[16][264];
    __shared__ float os[16][132];
    int t = threadIdx.x, i0 = blockIdx.x * 16;
    int wv = t >> 6, lane = t & 63;
    int eslot = lane >> 3, g = lane & 7;

    #pragma unroll
    for (int pp = 0; pp < 2; pp++) {
        int r = wv * 2 + pp, node = i0 + r;
        int s = offs[node], e = offs[node + 1];
        float acc0[16], acc1[16];
        #pragma unroll
        for (int q = 0; q < 16; q++) { acc0[q] = 0.f; acc1[q] = 0.f; }
        float w0s = 0.f, w1s = 0.f;
        for (int k0 = s; k0 < e; k0 += 8) {
            int k = k0 + eslot;
            bool valid = k < e;
            int j = valid ? elst[k] : 0;
            float2 wv2 = valid ? ew[k] : make_float2(0.f, 0.f);
            const float* xr = x + (size_t)j * GD + g * 16;
            float4 x0 = *(const float4*)(xr);
            float4 x1 = *(const float4*)(xr + 4);
            float4 x2 = *(const float4*)(xr + 8);
            float4 x3 = *(const float4*)(xr + 12);
            float xv[16] = {x0.x, x0.y, x0.z, x0.w, x1.x, x1.y, x1.z, x1.w,
                            x2.x, x2.y, x2.z, x2.w, x3.x, x3.y, x3.z, x3.w};
            #pragma unroll
            for (int q = 0; q < 16; q++) {
                acc0[q] += wv2.x * xv[q];
                acc1[q] += wv2.y * xv[q];
            }
            w0s += wv2.x; w1s += wv2.y;
        }
        #pragma unroll
        for (int m = 8; m <= 32; m <<= 1) {
            #pragma unroll
            for (int q = 0; q < 16; q++) {
                acc0[q] += __shfl_xor(acc0[q], m, 64);
                acc1[q] += __shfl_xor(acc1[q], m, 64);
            }
            w0s += __shfl_xor(w0s, m, 64);
            w1s += __shfl_xor(w1s, m, 64);
        }
        if (lane < 8) {
            float dn0 = 0.5f / w0s, dn1 = 0.5f / w1s;
            #pragma unroll
            for (int q = 0; q < 16; q += 2) {
                float a0 = acc0[q] * dn0, a1 = acc0[q + 1] * dn0;
                unsigned short h0 = f2rawbf(a0), h1 = f2rawbf(a1);
                *(unsigned*)&zh[r][lane * 16 + q] = (unsigned)h0 | ((unsigned)h1 << 16);
                *(unsigned*)&zl[r][lane * 16 + q] =
                    (unsigned)f2rawbf(a0 - rawbf2f(h0)) |
                    ((unsigned)f2rawbf(a1 - rawbf2f(h1)) << 16);
                float b0 = acc1[q] * dn1, b1 = acc1[q + 1] * dn1;
                unsigned short p0 = f2rawbf(b0), p1 = f2rawbf(b1);
                *(unsigned*)&zh[r][128 + lane * 16 + q] = (unsigned)p0 | ((unsigned)p1 << 16);
                *(unsigned*)&zl[r][128 + lane * 16 + q] =
                    (unsigned)f2rawbf(b0 - rawbf2f(p0)) |
                    ((unsigned)f2rawbf(b1 - rawbf2f(p1)) << 16);
            }
        }
    }
    __syncthreads();

    {
        int qd = lane >> 4, an = lane & 15;
        int c = wv * 16 + an;
        f32x4 acc = {0.f, 0.f, 0.f, 0.f};
        #pragma unroll
        for (int s = 0; s < 8; s++) {
            int ko = s * 32 + qd * 8;
            short8 ah = *(const short8*)&zh[an][ko];
            short8 al = *(const short8*)&zl[an][ko];
            short8 bh = *(const short8*)(Wth + (size_t)c * 256 + ko);
            short8 bl = *(const short8*)(Wtl + (size_t)c * 256 + ko);
            acc = __builtin_amdgcn_mfma_f32_16x16x32_bf16(ah, bh, acc, 0, 0, 0);
            acc = __builtin_amdgcn_mfma_f32_16x16x32_bf16(al, bh, acc, 0, 0, 0);
            acc = __builtin_amdgcn_mfma_f32_16x16x32_bf16(ah, bl, acc, 0, 0, 0);
        }
        #pragma unroll
        for (int r = 0; r < 4; r++) os[qd * 4 + r][c] = acc[r];
    }
    __syncthreads();

    #pragma unroll
    for (int pp = 0; pp < 2; pp++) {
        int r = wv * 2 + pp, node = i0 + r;
        float y0 = os[r][lane] + bias[lane];
        float y1 = os[r][lane + 64] + bias[lane + 64];
        float mu = wred(y0 + y1) * (1.f / 128.f);
        float c0 = y0 - mu, c1 = y1 - mu;
        float var = wred(c0 * c0 + c1 * c1) * (1.f / 128.f);
        float rs2 = 1.f / sqrtf(var + LN_EPS);
        float n0 = c0 * rs2 * gamma[lane] + beta[lane];
        float n1 = c1 * rs2 * gamma[lane + 64] + beta[lane + 64];
        n0 = n0 > 0.f ? n0 : 0.f;
        n1 = n1 > 0.f ? n1 : 0.f;
        out[(size_t)node * GD + lane]      = x[(size_t)node * GD + lane] + n0;
        out[(size_t)node * GD + lane + 64] = x[(size_t)node * GD + lane + 64] + n1;
    }
}

extern "C" void kernel_launch(void* const* d_in, const int* in_sizes, int n_in,
                              void* d_out, int out_size, void* d_ws, size_t ws_size,
                              hipStream_t stream) {
    const float* x       = (const float*)d_in[0];
    const float* W       = (const float*)d_in[2];
    const float* att_src = (const float*)d_in[3];
    const float* att_dst = (const float*)d_in[4];
    const float* bias    = (const float*)d_in[5];
    const float* gamma   = (const float*)d_in[6];
    const float* beta    = (const float*)d_in[7];
    float* out = (float*)d_out;

    char* w = (char*)d_ws;
    unsigned short* xa = (unsigned short*)w; w += (size_t)GN * 144 * 2;
    unsigned short* xb = (unsigned short*)w; w += (size_t)GN * 144 * 2;
    unsigned* cand = (unsigned*)w;           w += (size_t)GN * 128 * 4;
    float2* ew  = (float2*)w; w += (size_t)GN * GK * 8;
    unsigned short* Wth = (unsigned short*)w; w += (size_t)256 * 128 * 2;
    unsigned short* Wtl = (unsigned short*)w; w += (size_t)256 * 128 * 2;
    float* uvec = (float*)w; w += (size_t)4 * 128 * 4;
    float* sq   = (float*)w; w += (size_t)GN * 4;
    float* a_s  = (float*)w; w += (size_t)GN * GH * 4;
    float* a_d  = (float*)w; w += (size_t)GN * GH * 4;
    int*   fidx = (int*)w;   w += (size_t)GN * GK * 4;
    int*   cnt  = (int*)w;   w += (size_t)GN * 4;
    int*   curs = (int*)w;   w += (size_t)GN * 4;
    int*   offs = (int*)w;   w += (size_t)(GN + 1) * 4;
    int*   elst = (int*)w;   w += (size_t)GN * GK * 4;
    size_t need = (size_t)((char*)w - (char*)d_ws);
    if (ws_size < need) return;   // diagnostic guard

    k_prep<<<132 + GN / 4, 256, 0, stream>>>(W, att_src, att_dst, x, Wth, Wtl,
                                             uvec, sq, xa, xb, cnt, curs);
    k_gemm_topk<<<dim3(64, 32), 256, 0, stream>>>(xa, xb, cand);
    k_refine<<<GN / 4 + GN / 4, 256, 0, stream>>>(cand, x, sq, uvec, fidx, cnt, a_s, a_d);
    k_fill<<<GN * GK / 256, 256, 0, stream>>>(cnt, offs, fidx, curs, elst, a_s, a_d, ew);
    k_out<<<GN / 16, 512, 0, stream>>>(offs, elst, ew, x, Wth, Wtl, bias, gamma, beta, out);
}